// Round 3
// baseline (206.633 us; speedup 1.0000x reference)
//
#include <hip/hip_runtime.h>
#include <cstdint>
#include <cstddef>

#define MROWS 1024
#define NCOLS 4096
#define TOPK 8

typedef unsigned long long u64;
typedef unsigned int u32;

// Order-preserving float->u32 map (total order, matches score order exactly).
__device__ inline u32 fkey(u32 b) { return (b & 0x80000000u) ? ~b : (b | 0x80000000u); }

// key = (ord << 22) | ((1023-row) << 12) | (4095-col)   (54 bits used)
__device__ inline int key_col(u64 k) { return (NCOLS - 1) - (int)(k & 0xFFFull); }
__device__ inline int key_row(u64 k) { return (MROWS - 1) - (int)((k >> 12) & 0x3FFull); }

// single-wave LDS ordering fence: wait LDS only, do NOT drain vmcnt
#define WAVE_FENCE() __asm__ volatile("s_waitcnt lgkmcnt(0)" ::: "memory")

__device__ inline float wave_sum_f(float v) {
    #pragma unroll
    for (int off = 32; off >= 1; off >>= 1)
        v += __shfl_xor(v, off, 64);
    return v;
}
__device__ inline u64 wave_max_u64(u64 v) {
    #pragma unroll
    for (int off = 32; off >= 1; off >>= 1) {
        u64 o = __shfl_xor(v, off, 64);
        v = o > v ? o : v;
    }
    return v;
}
__device__ inline u64 umax64(u64 a, u64 b) { return a > b ? a : b; }

// wave max over distinct 54-bit keys: butterfly on high-32 only, then resolve
// the (wave-uniform, rare) high-word tie on the low 32 bits.
__device__ inline u64 wave_max_key(u64 v) {
    u32 h = (u32)(v >> 32);
    u32 hm = h;
    #pragma unroll
    for (int off = 32; off >= 1; off >>= 1) {
        u32 o = __shfl_xor(hm, off, 64);
        hm = o > hm ? o : hm;
    }
    u64 tie = __ballot(h == hm);
    if ((tie & (tie - 1ull)) == 0ull) {          // unique high word (common path)
        int src = __ffsll((long long)tie) - 1;
        return __shfl(v, src, 64);
    }
    u32 l = (h == hm) ? (u32)v : 0u;
    #pragma unroll
    for (int off = 32; off >= 1; off >>= 1) {
        u32 o = __shfl_xor(l, off, 64);
        l = o > l ? o : l;
    }
    return ((u64)hm << 32) | l;
}

// ---------------- K1: per-row top-8 score-keys + exp-sum ----------------------
// No bitmap/cont gating here: keys to done columns / from continuing rows are
// simply ignored by the match (coldone prune / inactive row). __expf: rel err
// ~3e-7, uniform scale cannot reorder; absmax verified unchanged (7.45e-9).
__global__ __launch_bounds__(256) void k_prep(const float* __restrict__ s,
                                              float* __restrict__ rowsum,
                                              u64* __restrict__ outkeys) {
    __shared__ u64 wavecand[4 * TOPK];
    __shared__ float fred[4];
    int r = blockIdx.x, t = threadIdx.x;
    int wid = t >> 6, lane = t & 63;

    const float4* s4 = (const float4*)(s + (size_t)r * NCOLS);
    u64 rowpart = (u64)(MROWS - 1 - r) << 12;
    u64 mykeys[16];
    float acc = 0.0f;
    #pragma unroll
    for (int i = 0; i < 4; ++i) {
        int f = t + i * 256;
        float4 v = s4[f];
        acc += __expf(v.x) + __expf(v.y) + __expf(v.z) + __expf(v.w);
        int c0 = 4 * f;
        float se[4] = {v.x, v.y, v.z, v.w};
        #pragma unroll
        for (int e = 0; e < 4; ++e) {
            int c = c0 + e;
            mykeys[i * 4 + e] = ((u64)fkey(__float_as_uint(se[e])) << 22) | rowpart |
                                (u64)(NCOLS - 1 - c);
        }
    }
    // per-row exp-sum partial
    acc = wave_sum_f(acc);
    if (lane == 0) fred[wid] = acc;
    __syncthreads();
    if (t == 0) rowsum[r] = fred[0] + fred[1] + fred[2] + fred[3];

    // per-wave top-8 (keys distinct -> unique winner each pass)
    u64 tmax = 0ull;
    #pragma unroll
    for (int k = 0; k < 16; ++k) tmax = umax64(tmax, mykeys[k]);
    for (int pass = 0; pass < TOPK; ++pass) {
        u64 w = wave_max_key(tmax);
        if (lane == 0) wavecand[wid * TOPK + pass] = w;
        if (tmax == w && w != 0ull) {
            #pragma unroll
            for (int k = 0; k < 16; ++k)
                if (mykeys[k] == w) mykeys[k] = 0ull;
            tmax = 0ull;
            #pragma unroll
            for (int k = 0; k < 16; ++k) tmax = umax64(tmax, mykeys[k]);
        }
    }
    __syncthreads();
    // wave 0 merges the 32 candidates -> true row top-8
    if (wid == 0) {
        u64 val = (lane < 32) ? wavecand[lane] : 0ull;
        for (int pass = 0; pass < TOPK; ++pass) {
            u64 g = wave_max_key(val);
            if (lane == 0) outkeys[(size_t)r * TOPK + pass] = g;
            if (val == g && g != 0ull) val = 0ull;
        }
    }
}

// ---------------- K2: block 0 = match (16 waves + serial tail); rest = policy --
// Phase A: dominant-edge rounds, 1 row/thread, keys in regs (v1 structure,
// identical to serial greedy since keys distinct; colbest tagged by round).
// Phase B: when <=96 rows remain, wave 0 finishes with exact serial greedy over
// their alive keys (LDS list) -- replaces the long barrier-round tail.
__global__ __launch_bounds__(1024) void k_policy_match(const float* __restrict__ s,
                                                       const int* __restrict__ cont,
                                                       const int* __restrict__ prev,
                                                       const float* __restrict__ rowsum,
                                                       const u64* __restrict__ keys_g,
                                                       float* __restrict__ policy,
                                                       float* __restrict__ actions) {
    __shared__ u64 colbest[NCOLS];             // 32 KiB (match only)
    __shared__ u64 list[1024];                 // 8 KiB  (phase-B tail list)
    __shared__ unsigned coldone[NCOLS / 32];   // 512 B
    __shared__ unsigned rowdone[MROWS / 32];   // 128 B
    __shared__ float act[MROWS];               // 4 KiB
    __shared__ float fredf[16];
    __shared__ int cnt;

    int t = threadIdx.x;

    if (blockIdx.x != 0) {
        // ---------------- policy row write (1024 thr, 1 float4/thr) -----------
        int r = blockIdx.x - 1;
        const float4* srow4 = (const float4*)(s + (size_t)r * NCOLS);
        float4 v = srow4[t];                   // issue early; flies during reduce
        int wid = t >> 6, lane = t & 63;
        float sv = rowsum[t];                  // 1024 partials, one per thread
        sv = wave_sum_f(sv);
        if (lane == 0) fredf[wid] = sv;
        __syncthreads();
        float g = 0.0f;
        #pragma unroll
        for (int i = 0; i < 16; ++i) g += fredf[i];   // same order every block
        float inv = 1.0f / g;
        float4* prow4 = (float4*)(policy + (size_t)r * NCOLS);
        float4 pv;
        pv.x = __expf(v.x) * inv;
        pv.y = __expf(v.y) * inv;
        pv.z = __expf(v.z) * inv;
        pv.w = __expf(v.w) * inv;
        prow4[t] = pv;
        return;
    }

    // ---------------- match: block 0, thread t owns row t ----------------------
    #pragma unroll
    for (int i = 0; i < 4; ++i) colbest[t + i * 1024] = 0ull;
    if (t < 128) coldone[t] = 0u;
    if (t < 32) rowdone[t] = 0u;
    if (t == 0) cnt = 0;
    __syncthreads();   // zeroing ordered before the atomics below

    int cgf = cont[t];
    int pv_ = prev[t];
    act[t] = cgf ? (float)pv_ : -1.0f;
    if (cgf) {
        atomicOr(&rowdone[t >> 5], 1u << (t & 31));
        atomicOr(&coldone[pv_ >> 5], 1u << (pv_ & 31));
    }
    bool active = (cgf == 0);

    u64 myk[TOPK];
    {
        const u64* gk = keys_g + (size_t)t * TOPK;
        #pragma unroll
        for (int k = 0; k < TOPK; ++k) myk[k] = gk[k];
    }
    __syncthreads();

    int anyleft = 1;
    for (int round = 1; round < 400; ++round) {
        u64 tag = (u64)round << 54;
        bool subm = false;
        u64 mybest = 0ull;
        int mycol = 0;
        if (active) {
            u64 best = 0ull;
            #pragma unroll
            for (int k = 0; k < TOPK; ++k) {
                u64 kk = myk[k];
                if (kk != 0ull) {
                    int c = key_col(kk);
                    if ((coldone[c >> 5] >> (c & 31)) & 1u) { myk[k] = 0ull; kk = 0ull; }
                }
                if (kk != 0ull) {
                    atomicMax((u64*)&colbest[key_col(kk)], tag | kk);
                    best = umax64(best, kk);
                }
            }
            if (best == 0ull) {
                active = false;                 // exhausted -> fallback catches
            } else {
                subm = true;
                mybest = best;
                mycol = key_col(best);
            }
        }
        anyleft = __syncthreads_count(active ? 1 : 0);
        if (anyleft == 0) break;
        if (subm && colbest[mycol] == (tag | mybest)) {
            act[t] = (float)mycol;
            atomicOr(&coldone[mycol >> 5], 1u << (mycol & 31));
            atomicOr(&rowdone[t >> 5], 1u << (t & 31));
            active = false;
        }
        __syncthreads();
        if (anyleft <= 96) break;              // commits visible; go serial tail
    }

    // ---- phase B: serial greedy over remaining alive keys (wave 0) ----------
    if (anyleft > 0) {
        if (active) {
            u64 tmp[TOPK];
            int nal = 0;
            #pragma unroll
            for (int k = 0; k < TOPK; ++k) {
                u64 kk = myk[k];
                if (kk == 0ull) continue;
                int c = key_col(kk);
                if ((coldone[c >> 5] >> (c & 31)) & 1u) continue;
                tmp[nal++] = kk;
            }
            if (nal) {
                int base = atomicAdd(&cnt, nal);
                if (base + nal <= 1024)        // overflow rows -> fallback
                    for (int i = 0; i < nal; ++i) list[base + i] = tmp[i];
            }
        }
        __syncthreads();
        if (t < 64) {
            int lane = t;
            int n = cnt; if (n > 1024) n = 1024;
            for (int iter = 0; iter < 200; ++iter) {
                u64 best = 0ull;
                for (int i = lane; i < n; i += 64) {
                    u64 kk = list[i];
                    if (kk == 0ull) continue;
                    int c = key_col(kk), rr = key_row(kk);
                    if (((coldone[c >> 5] >> (c & 31)) & 1u) ||
                        ((rowdone[rr >> 5] >> (rr & 31)) & 1u)) { list[i] = 0ull; continue; }
                    best = umax64(best, kk);
                }
                best = wave_max_key(best);
                if (best == 0ull) break;
                if (lane == 0) {
                    int rr = key_row(best), c = key_col(best);
                    act[rr] = (float)c;
                    coldone[c >> 5] |= 1u << (c & 31);
                    rowdone[rr >> 5] |= 1u << (rr & 31);
                }
                WAVE_FENCE();
            }
        }
    }
    __syncthreads();

    // ---- exact-greedy fallback for exhausted rows (P ~ 1e-5) ----------------
    if (t < 64) {
        int lane = t;
        unsigned miss = (lane < 32) ? ~rowdone[lane] : 0u;
        if (__ballot(miss != 0u) != 0ull) {
            for (int guard = 0; guard < 1200; ++guard) {
                u64 best = 0ull;
                for (int rr = 0; rr < MROWS; ++rr) {
                    if ((rowdone[rr >> 5] >> (rr & 31)) & 1u) continue;
                    const float* srow = s + (size_t)rr * NCOLS;
                    u64 rp = (u64)(MROWS - 1 - rr) << 12;
                    for (int c = lane; c < NCOLS; c += 64) {
                        if ((coldone[c >> 5] >> (c & 31)) & 1u) continue;
                        u64 kk = ((u64)fkey(__float_as_uint(srow[c])) << 22) | rp |
                                 (u64)(NCOLS - 1 - c);
                        best = umax64(best, kk);
                    }
                }
                best = wave_max_u64(best);
                if (best == 0ull) break;
                if (lane == 0) {
                    int row = key_row(best), col = key_col(best);
                    rowdone[row >> 5] |= 1u << (row & 31);
                    coldone[col >> 5] |= 1u << (col & 31);
                    act[row] = (float)col;
                }
                WAVE_FENCE();
            }
        }
    }
    __syncthreads();
    actions[t] = act[t];
}

extern "C" void kernel_launch(void* const* d_in, const int* in_sizes, int n_in,
                              void* d_out, int out_size, void* d_ws, size_t ws_size,
                              hipStream_t stream) {
    (void)in_sizes; (void)n_in; (void)out_size; (void)ws_size;
    const float* scores = (const float*)d_in[0];
    const int* cont = (const int*)d_in[1];
    const int* prev = (const int*)d_in[2];
    float* out = (float*)d_out;
    float* actions = out;
    float* policy = out + MROWS;

    char* ws = (char*)d_ws;
    float* rowsum = (float*)(ws + 0);            // 1024 f
    u64* keys8 = (u64*)(ws + 8192);              // 8192 u64

    k_prep<<<MROWS, 256, 0, stream>>>(scores, rowsum, keys8);
    k_policy_match<<<MROWS + 1, 1024, 0, stream>>>(scores, cont, prev, rowsum,
                                                   keys8, policy, actions);
}

// Round 4
// 106.062 us; speedup vs baseline: 1.9482x; 1.9482x over previous
//
#include <hip/hip_runtime.h>
#include <cstdint>
#include <cstddef>

#define MROWS 1024
#define NCOLS 4096
#define TOPK 16

typedef unsigned long long u64;
typedef unsigned int u32;

// Order-preserving float->u32 map (total order, matches score order exactly).
__device__ inline u32 fkey(u32 b) { return (b & 0x80000000u) ? ~b : (b | 0x80000000u); }

// key = (ord << 22) | ((1023-row) << 12) | (4095-col)   (54 bits used)
__device__ inline int key_col(u64 k) { return (NCOLS - 1) - (int)(k & 0xFFFull); }
__device__ inline int key_row(u64 k) { return (MROWS - 1) - (int)((k >> 12) & 0x3FFull); }

// single-wave LDS ordering fence: wait LDS only, do NOT drain vmcnt
#define WAVE_FENCE() __asm__ volatile("s_waitcnt lgkmcnt(0)" ::: "memory")

__device__ inline float wave_sum_f(float v) {
    #pragma unroll
    for (int off = 32; off >= 1; off >>= 1)
        v += __shfl_xor(v, off, 64);
    return v;
}
__device__ inline u64 wave_max_u64(u64 v) {
    #pragma unroll
    for (int off = 32; off >= 1; off >>= 1) {
        u64 o = __shfl_xor(v, off, 64);
        v = o > v ? o : v;
    }
    return v;
}
__device__ inline u64 umax64(u64 a, u64 b) { return a > b ? a : b; }

// In-register bitonic sort of 16 u64, DESCENDING. All indices compile-time.
__device__ inline void sort16_desc(u64* a) {
    #pragma unroll
    for (int k = 2; k <= 16; k <<= 1) {
        #pragma unroll
        for (int j = k >> 1; j > 0; j >>= 1) {
            #pragma unroll
            for (int i = 0; i < 16; ++i) {
                int l = i ^ j;
                if (l > i) {
                    bool up = ((i & k) == 0);
                    u64 x = a[i], y = a[l];
                    bool sw = up ? (x < y) : (x > y);
                    a[i] = sw ? y : x;
                    a[l] = sw ? x : y;
                }
            }
        }
    }
}
// Bitonic merge (16, descending): input bitonic, output sorted descending.
__device__ inline void bmerge16_desc(u64* a) {
    #pragma unroll
    for (int j = 8; j > 0; j >>= 1) {
        #pragma unroll
        for (int i = 0; i < 16; ++i) {
            int l = i ^ j;
            if (l > i) {
                u64 x = a[i], y = a[l];
                bool sw = (x < y);
                a[i] = sw ? y : x;
                a[l] = sw ? x : y;
            }
        }
    }
}

// ---------------- K1: per-row top-16 score-keys + exp-sum ---------------------
// Per-thread register bitonic sort-16 (VALU only, no cross-lane chains), then
// an 8-level LDS merge tree of sorted-16 lists. No bitmap prefilter: TOPK=16
// depth makes exhaustion negligible; keys to done cols pruned in the match.
__global__ __launch_bounds__(256) void k_prep(const float* __restrict__ s,
                                              float* __restrict__ rowsum,
                                              u64* __restrict__ outkeys) {
    __shared__ u64 lists[16][256];   // 32 KiB, transposed: elem i of thread t
    __shared__ float fred[4];
    int r = blockIdx.x, t = threadIdx.x;
    int wid = t >> 6, lane = t & 63;

    const float4* s4 = (const float4*)(s + (size_t)r * NCOLS);
    u64 rowpart = (u64)(MROWS - 1 - r) << 12;
    u64 a[16];
    float acc = 0.0f;
    #pragma unroll
    for (int i = 0; i < 4; ++i) {
        int f = t + i * 256;
        float4 v = s4[f];
        acc += __expf(v.x) + __expf(v.y) + __expf(v.z) + __expf(v.w);
        int c0 = 4 * f;
        a[i * 4 + 0] = ((u64)fkey(__float_as_uint(v.x)) << 22) | rowpart | (u64)(NCOLS - 1 - (c0 + 0));
        a[i * 4 + 1] = ((u64)fkey(__float_as_uint(v.y)) << 22) | rowpart | (u64)(NCOLS - 1 - (c0 + 1));
        a[i * 4 + 2] = ((u64)fkey(__float_as_uint(v.z)) << 22) | rowpart | (u64)(NCOLS - 1 - (c0 + 2));
        a[i * 4 + 3] = ((u64)fkey(__float_as_uint(v.w)) << 22) | rowpart | (u64)(NCOLS - 1 - (c0 + 3));
    }

    sort16_desc(a);                      // my 16 keys, descending

    acc = wave_sum_f(acc);
    if (lane == 0) fred[wid] = acc;

    #pragma unroll
    for (int i = 0; i < 16; ++i) lists[i][t] = a[i];
    __syncthreads();
    if (t == 0) rowsum[r] = fred[0] + fred[1] + fred[2] + fred[3];

    // merge tree: 256 sorted-16 lists -> row top-16 (true prefix, sorted)
    #pragma unroll
    for (int s_ = 128; s_ >= 1; s_ >>= 1) {
        if (t < s_) {
            u64 b[16];
            #pragma unroll
            for (int i = 0; i < 16; ++i) b[i] = lists[i][t + s_];
            // half-cleaner: top-16 of (a desc ++ b desc), bitonic result
            #pragma unroll
            for (int i = 0; i < 16; ++i) {
                u64 x = a[i], y = b[15 - i];
                a[i] = x > y ? x : y;
            }
            bmerge16_desc(a);
            #pragma unroll
            for (int i = 0; i < 16; ++i) lists[i][t] = a[i];
        }
        __syncthreads();
    }
    if (t == 0) {
        #pragma unroll
        for (int i = 0; i < 16; ++i) outkeys[(size_t)r * TOPK + i] = a[i];
    }
}

// ---------------- K2: block 0 = match (parallel rounds); rest = policy --------
// Match: dominant-edge rounds, 512 threads x 2 rows, keys in regs (top-16
// prefix per row => identical to serial greedy; colbest tagged by round).
// Runs to completion; exact full-rescan fallback only for exhausted rows.
__global__ __launch_bounds__(512) void k_policy_match(const float* __restrict__ s,
                                                      const int* __restrict__ cont,
                                                      const int* __restrict__ prev,
                                                      const float* __restrict__ rowsum,
                                                      const u64* __restrict__ keys_g,
                                                      float* __restrict__ policy,
                                                      float* __restrict__ actions) {
    __shared__ u64 colbest[NCOLS];             // 32 KiB (match only)
    __shared__ unsigned coldone[NCOLS / 32];   // 512 B
    __shared__ unsigned rowdone[MROWS / 32];   // 128 B
    __shared__ float act[MROWS];               // 4 KiB
    __shared__ float fredf[8];

    int t = threadIdx.x;
    int wid = t >> 6, lane = t & 63;

    if (blockIdx.x != 0) {
        // ---------------- policy row write (512 thr, 2 float4/thr) ------------
        int r = blockIdx.x - 1;
        const float4* srow4 = (const float4*)(s + (size_t)r * NCOLS);
        float4 v0 = srow4[t], v1 = srow4[t + 512];   // fly during the reduce
        float sv = rowsum[t] + rowsum[t + 512];
        sv = wave_sum_f(sv);
        if (lane == 0) fredf[wid] = sv;
        __syncthreads();
        float g = 0.0f;
        #pragma unroll
        for (int i = 0; i < 8; ++i) g += fredf[i];   // same order every block
        float inv = 1.0f / g;
        float4* prow4 = (float4*)(policy + (size_t)r * NCOLS);
        float4 p;
        p.x = __expf(v0.x) * inv; p.y = __expf(v0.y) * inv;
        p.z = __expf(v0.z) * inv; p.w = __expf(v0.w) * inv;
        prow4[t] = p;
        p.x = __expf(v1.x) * inv; p.y = __expf(v1.y) * inv;
        p.z = __expf(v1.z) * inv; p.w = __expf(v1.w) * inv;
        prow4[t + 512] = p;
        return;
    }

    // ---------------- match: thread t owns rows t and t+512 -------------------
    #pragma unroll
    for (int i = 0; i < 8; ++i) colbest[t + i * 512] = 0ull;
    if (t < 128) coldone[t] = 0u;
    if (t < 32) rowdone[t] = 0u;
    __syncthreads();   // zeroing ordered before the atomics below

    int r0 = t, r1 = t + 512;
    int c0f = cont[r0], c1f = cont[r1];
    int p0 = prev[r0], p1 = prev[r1];
    act[r0] = c0f ? (float)p0 : -1.0f;
    act[r1] = c1f ? (float)p1 : -1.0f;
    if (c0f) {
        atomicOr(&rowdone[r0 >> 5], 1u << (r0 & 31));
        atomicOr(&coldone[p0 >> 5], 1u << (p0 & 31));
    }
    if (c1f) {
        atomicOr(&rowdone[r1 >> 5], 1u << (r1 & 31));
        atomicOr(&coldone[p1 >> 5], 1u << (p1 & 31));
    }
    bool act0 = (c0f == 0), act1 = (c1f == 0);
    bool exh = false;

    u64 k0[TOPK], k1[TOPK];
    {
        const u64* g0 = keys_g + (size_t)r0 * TOPK;
        const u64* g1 = keys_g + (size_t)r1 * TOPK;
        #pragma unroll
        for (int k = 0; k < TOPK; ++k) { k0[k] = g0[k]; k1[k] = g1[k]; }
    }
    __syncthreads();

    int left = 1;
    for (int round = 1; round < 400; ++round) {
        u64 tag = (u64)round << 54;
        bool sub0 = false, sub1 = false;
        u64 best0 = 0ull, best1 = 0ull;
        if (act0) {
            u64 best = 0ull;
            #pragma unroll
            for (int k = 0; k < TOPK; ++k) {
                u64 kk = k0[k];
                if (kk != 0ull) {
                    int c = key_col(kk);
                    if ((coldone[c >> 5] >> (c & 31)) & 1u) { k0[k] = 0ull; kk = 0ull; }
                }
                if (kk != 0ull) {
                    atomicMax((u64*)&colbest[key_col(kk)], tag | kk);
                    best = umax64(best, kk);
                }
            }
            if (best == 0ull) { act0 = false; exh = true; }
            else { sub0 = true; best0 = best; }
        }
        if (act1) {
            u64 best = 0ull;
            #pragma unroll
            for (int k = 0; k < TOPK; ++k) {
                u64 kk = k1[k];
                if (kk != 0ull) {
                    int c = key_col(kk);
                    if ((coldone[c >> 5] >> (c & 31)) & 1u) { k1[k] = 0ull; kk = 0ull; }
                }
                if (kk != 0ull) {
                    atomicMax((u64*)&colbest[key_col(kk)], tag | kk);
                    best = umax64(best, kk);
                }
            }
            if (best == 0ull) { act1 = false; exh = true; }
            else { sub1 = true; best1 = best; }
        }
        left = __syncthreads_count((act0 || act1) ? 1 : 0);
        if (left == 0) break;
        if (sub0 && act0) {
            int c = key_col(best0);
            if (colbest[c] == (tag | best0)) {
                unsigned old = atomicOr(&coldone[c >> 5], 1u << (c & 31));
                if (!(old & (1u << (c & 31)))) {
                    act[r0] = (float)c;
                    atomicOr(&rowdone[r0 >> 5], 1u << (r0 & 31));
                    act0 = false;
                }
            }
        }
        if (sub1 && act1) {
            int c = key_col(best1);
            if (colbest[c] == (tag | best1)) {
                unsigned old = atomicOr(&coldone[c >> 5], 1u << (c & 31));
                if (!(old & (1u << (c & 31)))) {
                    act[r1] = (float)c;
                    atomicOr(&rowdone[r1 >> 5], 1u << (r1 & 31));
                    act1 = false;
                }
            }
        }
        __syncthreads();   // commits visible before next scan
    }
    __syncthreads();

    // ---- exact-greedy fallback for exhausted rows (P ~ 1e-7 at depth 16) -----
    if (t < 64) {
        unsigned miss = (t < 32) ? ~rowdone[t] : 0u;
        if (__ballot(miss != 0u) != 0ull) {
            for (int guard = 0; guard < 1200; ++guard) {
                u64 best = 0ull;
                for (int rr = 0; rr < MROWS; ++rr) {
                    if ((rowdone[rr >> 5] >> (rr & 31)) & 1u) continue;
                    const float* srow = s + (size_t)rr * NCOLS;
                    u64 rp = (u64)(MROWS - 1 - rr) << 12;
                    for (int c = t; c < NCOLS; c += 64) {
                        if ((coldone[c >> 5] >> (c & 31)) & 1u) continue;
                        u64 kk = ((u64)fkey(__float_as_uint(srow[c])) << 22) | rp |
                                 (u64)(NCOLS - 1 - c);
                        best = umax64(best, kk);
                    }
                }
                best = wave_max_u64(best);
                if (best == 0ull) break;
                if (t == 0) {
                    int row = key_row(best), col = key_col(best);
                    rowdone[row >> 5] |= 1u << (row & 31);
                    coldone[col >> 5] |= 1u << (col & 31);
                    act[row] = (float)col;
                }
                WAVE_FENCE();
            }
        }
    }
    __syncthreads();
    actions[t] = act[t];
    actions[t + 512] = act[t + 512];
}

extern "C" void kernel_launch(void* const* d_in, const int* in_sizes, int n_in,
                              void* d_out, int out_size, void* d_ws, size_t ws_size,
                              hipStream_t stream) {
    (void)in_sizes; (void)n_in; (void)out_size; (void)ws_size;
    const float* scores = (const float*)d_in[0];
    const int* cont = (const int*)d_in[1];
    const int* prev = (const int*)d_in[2];
    float* out = (float*)d_out;
    float* actions = out;
    float* policy = out + MROWS;

    char* ws = (char*)d_ws;
    float* rowsum = (float*)(ws + 0);            // 1024 f
    u64* keys16 = (u64*)(ws + 8192);             // 1024*16 u64 = 128 KiB

    k_prep<<<MROWS, 256, 0, stream>>>(scores, rowsum, keys16);
    k_policy_match<<<MROWS + 1, 512, 0, stream>>>(scores, cont, prev, rowsum,
                                                  keys16, policy, actions);
}

// Round 5
// 101.591 us; speedup vs baseline: 2.0340x; 1.0440x over previous
//
#include <hip/hip_runtime.h>
#include <cstdint>
#include <cstddef>

#define MROWS 1024
#define NCOLS 4096
#define TOPK 16

typedef unsigned long long u64;
typedef unsigned int u32;

// Order-preserving float->u32 map (total order, matches score order exactly).
__device__ inline u32 fkey(u32 b) { return (b & 0x80000000u) ? ~b : (b | 0x80000000u); }

// key = (ord << 22) | ((1023-row) << 12) | (4095-col)   (54 bits used)
__device__ inline int key_col(u64 k) { return (NCOLS - 1) - (int)(k & 0xFFFull); }
__device__ inline int key_row(u64 k) { return (MROWS - 1) - (int)((k >> 12) & 0x3FFull); }

// single-wave LDS ordering fence: wait LDS only, do NOT drain vmcnt
#define WAVE_FENCE() __asm__ volatile("s_waitcnt lgkmcnt(0)" ::: "memory")

__device__ inline float wave_sum_f(float v) {
    #pragma unroll
    for (int off = 32; off >= 1; off >>= 1)
        v += __shfl_xor(v, off, 64);
    return v;
}
__device__ inline u64 wave_max_u64(u64 v) {
    #pragma unroll
    for (int off = 32; off >= 1; off >>= 1) {
        u64 o = __shfl_xor(v, off, 64);
        v = o > v ? o : v;
    }
    return v;
}
__device__ inline u64 umax64(u64 a, u64 b) { return a > b ? a : b; }

// In-register bitonic sort of 16 u64, DESCENDING. All indices compile-time.
__device__ inline void sort16_desc(u64* a) {
    #pragma unroll
    for (int k = 2; k <= 16; k <<= 1) {
        #pragma unroll
        for (int j = k >> 1; j > 0; j >>= 1) {
            #pragma unroll
            for (int i = 0; i < 16; ++i) {
                int l = i ^ j;
                if (l > i) {
                    bool up = ((i & k) == 0);
                    u64 x = a[i], y = a[l];
                    bool sw = up ? (x < y) : (x > y);
                    a[i] = sw ? y : x;
                    a[l] = sw ? x : y;
                }
            }
        }
    }
}
// Bitonic merge (16, descending): input bitonic, output sorted descending.
__device__ inline void bmerge16_desc(u64* a) {
    #pragma unroll
    for (int j = 8; j > 0; j >>= 1) {
        #pragma unroll
        for (int i = 0; i < 16; ++i) {
            int l = i ^ j;
            if (l > i) {
                u64 x = a[i], y = a[l];
                bool sw = (x < y);
                a[i] = sw ? y : x;
                a[l] = sw ? x : y;
            }
        }
    }
}

// ---------------- K1: per-row top-16 score-keys + exp-sum ---------------------
// Per-thread register bitonic sort-16 (VALU only), then an LDS merge tree.
// Levels <=64 are wave-0-internal: s_waitcnt fence instead of __syncthreads.
__global__ __launch_bounds__(256, 1) void k_prep(const float* __restrict__ s,
                                                 float* __restrict__ rowsum,
                                                 u64* __restrict__ outkeys) {
    __shared__ u64 lists[16][256];   // 32 KiB, transposed: elem i of thread t
    __shared__ float fred[4];
    int r = blockIdx.x, t = threadIdx.x;
    int wid = t >> 6, lane = t & 63;

    const float4* s4 = (const float4*)(s + (size_t)r * NCOLS);
    u64 rowpart = (u64)(MROWS - 1 - r) << 12;
    u64 a[16];
    float acc = 0.0f;
    #pragma unroll
    for (int i = 0; i < 4; ++i) {
        int f = t + i * 256;
        float4 v = s4[f];
        acc += __expf(v.x) + __expf(v.y) + __expf(v.z) + __expf(v.w);
        int c0 = 4 * f;
        a[i * 4 + 0] = ((u64)fkey(__float_as_uint(v.x)) << 22) | rowpart | (u64)(NCOLS - 1 - (c0 + 0));
        a[i * 4 + 1] = ((u64)fkey(__float_as_uint(v.y)) << 22) | rowpart | (u64)(NCOLS - 1 - (c0 + 1));
        a[i * 4 + 2] = ((u64)fkey(__float_as_uint(v.z)) << 22) | rowpart | (u64)(NCOLS - 1 - (c0 + 2));
        a[i * 4 + 3] = ((u64)fkey(__float_as_uint(v.w)) << 22) | rowpart | (u64)(NCOLS - 1 - (c0 + 3));
    }

    sort16_desc(a);                      // my 16 keys, descending

    acc = wave_sum_f(acc);
    if (lane == 0) fred[wid] = acc;

    #pragma unroll
    for (int i = 0; i < 16; ++i) lists[i][t] = a[i];
    __syncthreads();
    if (t == 0) rowsum[r] = fred[0] + fred[1] + fred[2] + fred[3];

    // level 128 (cross-wave): threads 0..127 merge with 128..255
    if (t < 128) {
        u64 b[16];
        #pragma unroll
        for (int i = 0; i < 16; ++i) b[i] = lists[i][t + 128];
        #pragma unroll
        for (int i = 0; i < 16; ++i) {
            u64 x = a[i], y = b[15 - i];
            a[i] = x > y ? x : y;
        }
        bmerge16_desc(a);
        #pragma unroll
        for (int i = 0; i < 16; ++i) lists[i][t] = a[i];
    }
    __syncthreads();

    // levels 64..1: wave-0-internal (writers/readers all in wave 0 after the
    // barrier above), so a lgkmcnt fence replaces __syncthreads.
    if (t < 64) {
        #pragma unroll
        for (int s_ = 64; s_ >= 1; s_ >>= 1) {
            if (t < s_) {
                u64 b[16];
                #pragma unroll
                for (int i = 0; i < 16; ++i) b[i] = lists[i][t + s_];
                #pragma unroll
                for (int i = 0; i < 16; ++i) {
                    u64 x = a[i], y = b[15 - i];
                    a[i] = x > y ? x : y;
                }
                bmerge16_desc(a);
                if (s_ > 1) {
                    #pragma unroll
                    for (int i = 0; i < 16; ++i) lists[i][t] = a[i];
                }
            }
            WAVE_FENCE();
        }
        if (t == 0) {
            #pragma unroll
            for (int i = 0; i < 16; ++i) outkeys[(size_t)r * TOPK + i] = a[i];
        }
    }
}

// Batched prune: issue all 16 coldone word-loads independently (one lgkmcnt
// drain, not 16 serial ~120cy probes), then prune registers-only.
__device__ inline u64 prune_and_best(u64* kk, const unsigned* coldone) {
    u32 cw[TOPK];
    #pragma unroll
    for (int k = 0; k < TOPK; ++k) {
        int c = key_col(kk[k]);          // dead key -> col 4095, harmless read
        cw[k] = coldone[c >> 5];
    }
    u64 best = 0ull;
    #pragma unroll
    for (int k = 0; k < TOPK; ++k) {
        int c = key_col(kk[k]);
        if ((cw[k] >> (c & 31)) & 1u) kk[k] = 0ull;
        best = umax64(best, kk[k]);
    }
    return best;
}

// ---------------- K2: block 0 = match (parallel rounds); rest = policy --------
// Match: dominant-edge rounds, 512 threads x 2 rows, keys in REGISTERS
// (launch_bounds(512,1) lifts the VGPR cap that forced scratch spill before).
// Identical to serial greedy since keys distinct; colbest tagged by round.
__global__ __launch_bounds__(512, 1) void k_policy_match(const float* __restrict__ s,
                                                         const int* __restrict__ cont,
                                                         const int* __restrict__ prev,
                                                         const float* __restrict__ rowsum,
                                                         const u64* __restrict__ keys_g,
                                                         float* __restrict__ policy,
                                                         float* __restrict__ actions) {
    __shared__ u64 colbest[NCOLS];             // 32 KiB (match only)
    __shared__ unsigned coldone[NCOLS / 32];   // 512 B
    __shared__ unsigned rowdone[MROWS / 32];   // 128 B
    __shared__ float act[MROWS];               // 4 KiB
    __shared__ float fredf[8];

    int t = threadIdx.x;
    int wid = t >> 6, lane = t & 63;

    if (blockIdx.x != 0) {
        // ---------------- policy row write (512 thr, 2 float4/thr) ------------
        int r = blockIdx.x - 1;
        const float4* srow4 = (const float4*)(s + (size_t)r * NCOLS);
        float4 v0 = srow4[t], v1 = srow4[t + 512];   // fly during the reduce
        float sv = rowsum[t] + rowsum[t + 512];
        sv = wave_sum_f(sv);
        if (lane == 0) fredf[wid] = sv;
        __syncthreads();
        float g = 0.0f;
        #pragma unroll
        for (int i = 0; i < 8; ++i) g += fredf[i];   // same order every block
        float inv = 1.0f / g;
        float4* prow4 = (float4*)(policy + (size_t)r * NCOLS);
        float4 p;
        p.x = __expf(v0.x) * inv; p.y = __expf(v0.y) * inv;
        p.z = __expf(v0.z) * inv; p.w = __expf(v0.w) * inv;
        prow4[t] = p;
        p.x = __expf(v1.x) * inv; p.y = __expf(v1.y) * inv;
        p.z = __expf(v1.z) * inv; p.w = __expf(v1.w) * inv;
        prow4[t + 512] = p;
        return;
    }

    // ---------------- match: thread t owns rows t and t+512 -------------------
    #pragma unroll
    for (int i = 0; i < 8; ++i) colbest[t + i * 512] = 0ull;
    if (t < 128) coldone[t] = 0u;
    if (t < 32) rowdone[t] = 0u;
    __syncthreads();   // zeroing ordered before the atomics below

    int r0 = t, r1 = t + 512;
    int c0f = cont[r0], c1f = cont[r1];
    int p0 = prev[r0], p1 = prev[r1];
    act[r0] = c0f ? (float)p0 : -1.0f;
    act[r1] = c1f ? (float)p1 : -1.0f;
    if (c0f) {
        atomicOr(&rowdone[r0 >> 5], 1u << (r0 & 31));
        atomicOr(&coldone[p0 >> 5], 1u << (p0 & 31));
    }
    if (c1f) {
        atomicOr(&rowdone[r1 >> 5], 1u << (r1 & 31));
        atomicOr(&coldone[p1 >> 5], 1u << (p1 & 31));
    }
    bool act0 = (c0f == 0), act1 = (c1f == 0);

    u64 k0[TOPK], k1[TOPK];
    {
        const u64* g0 = keys_g + (size_t)r0 * TOPK;
        const u64* g1 = keys_g + (size_t)r1 * TOPK;
        #pragma unroll
        for (int k = 0; k < TOPK; ++k) { k0[k] = g0[k]; k1[k] = g1[k]; }
    }
    __syncthreads();

    for (int round = 1; round < 400; ++round) {
        u64 tag = (u64)round << 54;
        bool sub0 = false, sub1 = false;
        u64 best0 = 0ull, best1 = 0ull;
        if (act0) {
            best0 = prune_and_best(k0, coldone);
            if (best0 == 0ull) act0 = false;      // exhausted -> fallback later
            else {
                sub0 = true;
                #pragma unroll
                for (int k = 0; k < TOPK; ++k)
                    if (k0[k] != 0ull)
                        atomicMax((u64*)&colbest[key_col(k0[k])], tag | k0[k]);
            }
        }
        if (act1) {
            best1 = prune_and_best(k1, coldone);
            if (best1 == 0ull) act1 = false;
            else {
                sub1 = true;
                #pragma unroll
                for (int k = 0; k < TOPK; ++k)
                    if (k1[k] != 0ull)
                        atomicMax((u64*)&colbest[key_col(k1[k])], tag | k1[k]);
            }
        }
        __syncthreads();                          // submissions visible
        // batched commit probes (independent LDS reads)
        u64 cb0 = sub0 ? colbest[key_col(best0)] : 0ull;
        u64 cb1 = sub1 ? colbest[key_col(best1)] : 0ull;
        if (sub0 && cb0 == (tag | best0)) {
            int c = key_col(best0);
            unsigned old = atomicOr(&coldone[c >> 5], 1u << (c & 31));
            if (!(old & (1u << (c & 31)))) {
                act[r0] = (float)c;
                atomicOr(&rowdone[r0 >> 5], 1u << (r0 & 31));
                act0 = false;
            }
        }
        if (sub1 && cb1 == (tag | best1)) {
            int c = key_col(best1);
            unsigned old = atomicOr(&coldone[c >> 5], 1u << (c & 31));
            if (!(old & (1u << (c & 31)))) {
                act[r1] = (float)c;
                atomicOr(&rowdone[r1 >> 5], 1u << (r1 & 31));
                act1 = false;
            }
        }
        int left = __syncthreads_count((act0 || act1) ? 1 : 0);  // commit barrier
        if (left == 0) break;
    }
    __syncthreads();

    // ---- exact-greedy fallback for exhausted rows (P ~ 1e-7 at depth 16) -----
    if (t < 64) {
        unsigned miss = (t < 32) ? ~rowdone[t] : 0u;
        if (__ballot(miss != 0u) != 0ull) {
            for (int guard = 0; guard < 1200; ++guard) {
                u64 best = 0ull;
                for (int rr = 0; rr < MROWS; ++rr) {
                    if ((rowdone[rr >> 5] >> (rr & 31)) & 1u) continue;
                    const float* srow = s + (size_t)rr * NCOLS;
                    u64 rp = (u64)(MROWS - 1 - rr) << 12;
                    for (int c = t; c < NCOLS; c += 64) {
                        if ((coldone[c >> 5] >> (c & 31)) & 1u) continue;
                        u64 kk = ((u64)fkey(__float_as_uint(srow[c])) << 22) | rp |
                                 (u64)(NCOLS - 1 - c);
                        best = umax64(best, kk);
                    }
                }
                best = wave_max_u64(best);
                if (best == 0ull) break;
                if (t == 0) {
                    int row = key_row(best), col = key_col(best);
                    rowdone[row >> 5] |= 1u << (row & 31);
                    coldone[col >> 5] |= 1u << (col & 31);
                    act[row] = (float)col;
                }
                WAVE_FENCE();
            }
        }
    }
    __syncthreads();
    actions[t] = act[t];
    actions[t + 512] = act[t + 512];
}

extern "C" void kernel_launch(void* const* d_in, const int* in_sizes, int n_in,
                              void* d_out, int out_size, void* d_ws, size_t ws_size,
                              hipStream_t stream) {
    (void)in_sizes; (void)n_in; (void)out_size; (void)ws_size;
    const float* scores = (const float*)d_in[0];
    const int* cont = (const int*)d_in[1];
    const int* prev = (const int*)d_in[2];
    float* out = (float*)d_out;
    float* actions = out;
    float* policy = out + MROWS;

    char* ws = (char*)d_ws;
    float* rowsum = (float*)(ws + 0);            // 1024 f
    u64* keys16 = (u64*)(ws + 8192);             // 1024*16 u64 = 128 KiB

    k_prep<<<MROWS, 256, 0, stream>>>(scores, rowsum, keys16);
    k_policy_match<<<MROWS + 1, 512, 0, stream>>>(scores, cont, prev, rowsum,
                                                  keys16, policy, actions);
}